// Round 1
// baseline (49.978 us; speedup 1.0000x reference)
//
#include <hip/hip_runtime.h>

#define DW 512
#define DH 512
#define RROWS 8
#define BORDER (-2.0f)

__global__ __launch_bounds__(256) void dilate3x3_kernel(
    const float* __restrict__ in, float* __restrict__ out) {
    const int tx = threadIdx.x;                 // 0..127 covers full width (512/4)
    const int x0 = tx << 2;                     // float4-aligned column start
    const int rowgrp = blockIdx.y * blockDim.y + threadIdx.y;
    const int y0 = rowgrp * RROWS;
    const int img = blockIdx.z;

    const float* __restrict__ p = in  + (size_t)img * DH * DW;
    float*       __restrict__ q = out + (size_t)img * DH * DW;

    // rolling horizontal-max buffers for 3 consecutive input rows
    float h[3][4];

    auto loadrow = [&](int y, float hv[4]) {
        if (y < 0 || y >= DH) {
            hv[0] = hv[1] = hv[2] = hv[3] = BORDER;
            return;
        }
        const float* row = p + (size_t)y * DW;
        float4 a = *reinterpret_cast<const float4*>(row + x0);
        float left  = (x0 == 0)       ? BORDER : row[x0 - 1];
        float right = (x0 + 4 >= DW)  ? BORDER : row[x0 + 4];
        hv[0] = fmaxf(fmaxf(left, a.x), a.y);
        hv[1] = fmaxf(fmaxf(a.x, a.y), a.z);
        hv[2] = fmaxf(fmaxf(a.y, a.z), a.w);
        hv[3] = fmaxf(fmaxf(a.z, a.w), right);
    };

    loadrow(y0 - 1, h[0]);
    loadrow(y0,     h[1]);

    #pragma unroll
    for (int r = 0; r < RROWS; ++r) {
        loadrow(y0 + r + 1, h[(r + 2) % 3]);
        float4 o;
        // max over the three live row-buffers (order irrelevant: commutative)
        o.x = fmaxf(fmaxf(h[0][0], h[1][0]), h[2][0]);
        o.y = fmaxf(fmaxf(h[0][1], h[1][1]), h[2][1]);
        o.z = fmaxf(fmaxf(h[0][2], h[1][2]), h[2][2]);
        o.w = fmaxf(fmaxf(h[0][3], h[1][3]), h[2][3]);
        *reinterpret_cast<float4*>(q + (size_t)(y0 + r) * DW + x0) = o;
    }
}

extern "C" void kernel_launch(void* const* d_in, const int* in_sizes, int n_in,
                              void* d_out, int out_size, void* d_ws, size_t ws_size,
                              hipStream_t stream) {
    const float* img = (const float*)d_in[0];
    float* out = (float*)d_out;

    const int n_imgs = in_sizes[0] / (DH * DW);   // 16*8 = 128

    dim3 block(128, 2, 1);                        // 256 threads
    dim3 grid(1, DH / (RROWS * 2), n_imgs);       // (1, 32, 128)
    dilate3x3_kernel<<<grid, block, 0, stream>>>(img, out);
}

// Round 3
// 49.363 us; speedup vs baseline: 1.0125x; 1.0125x over previous
//
#include <hip/hip_runtime.h>

#define DW 512
#define DH 512
#define RROWS 8
#define BORDER (-2.0f)

typedef float v4f __attribute__((ext_vector_type(4)));

__global__ __launch_bounds__(256) void dilate3x3_kernel(
    const float* __restrict__ in, float* __restrict__ out) {
    const int tx = threadIdx.x;                 // 0..127 covers full width (512/4)
    const int x0 = tx << 2;                     // float4-aligned column start
    const int rowgrp = blockIdx.y * blockDim.y + threadIdx.y;
    const int y0 = rowgrp * RROWS;
    const int img = blockIdx.z;

    const float* __restrict__ p = in  + (size_t)img * DH * DW;
    float*       __restrict__ q = out + (size_t)img * DH * DW;

    // rolling horizontal-max buffers for 3 consecutive input rows
    float h[3][4];

    auto loadrow = [&](int y, float hv[4]) {
        if (y < 0 || y >= DH) {
            hv[0] = hv[1] = hv[2] = hv[3] = BORDER;
            return;
        }
        const float* row = p + (size_t)y * DW;
        v4f a = *reinterpret_cast<const v4f*>(row + x0);
        float left  = (x0 == 0)       ? BORDER : row[x0 - 1];
        float right = (x0 + 4 >= DW)  ? BORDER : row[x0 + 4];
        hv[0] = fmaxf(fmaxf(left, a.x), a.y);
        hv[1] = fmaxf(fmaxf(a.x, a.y), a.z);
        hv[2] = fmaxf(fmaxf(a.y, a.z), a.w);
        hv[3] = fmaxf(fmaxf(a.z, a.w), right);
    };

    loadrow(y0 - 1, h[0]);
    loadrow(y0,     h[1]);

    #pragma unroll
    for (int r = 0; r < RROWS; ++r) {
        loadrow(y0 + r + 1, h[(r + 2) % 3]);
        v4f o;
        o.x = fmaxf(fmaxf(h[0][0], h[1][0]), h[2][0]);
        o.y = fmaxf(fmaxf(h[0][1], h[1][1]), h[2][1]);
        o.z = fmaxf(fmaxf(h[0][2], h[1][2]), h[2][2]);
        o.w = fmaxf(fmaxf(h[0][3], h[1][3]), h[2][3]);
        // Non-temporal store: output is never re-read; keep it out of L2/L3
        // so the input stays Infinity-Cache-resident across replays.
        __builtin_nontemporal_store(o,
            reinterpret_cast<v4f*>(q + (size_t)(y0 + r) * DW + x0));
    }
}

extern "C" void kernel_launch(void* const* d_in, const int* in_sizes, int n_in,
                              void* d_out, int out_size, void* d_ws, size_t ws_size,
                              hipStream_t stream) {
    const float* img = (const float*)d_in[0];
    float* out = (float*)d_out;

    const int n_imgs = in_sizes[0] / (DH * DW);   // 16*8 = 128

    dim3 block(128, 2, 1);                        // 256 threads
    dim3 grid(1, DH / (RROWS * 2), n_imgs);       // (1, 32, 128)
    dilate3x3_kernel<<<grid, block, 0, stream>>>(img, out);
}